// Round 17
// baseline (319.162 us; speedup 1.0000x reference)
//
#include <hip/hip_runtime.h>

// ---------- constants (problem is fixed-shape) ----------
#define LTOK 36864     // H*W = 192*192
#define DIMC 384
#define NHEADS 6
#define HDIM 64
#define HIDD 768
#define NWIN 12        // windows per side
#define WSZ 16
#define OWS 24
#define KVTOK 576      // 24*24

using bf16x8 = __attribute__((ext_vector_type(8))) short;
using f32x4  = __attribute__((ext_vector_type(4))) float;

__device__ inline unsigned short f2bf(float f) {
  unsigned u = __float_as_uint(f);
  return (unsigned short)((u + 0x7FFFu + ((u >> 16) & 1u)) >> 16);
}
__device__ inline float bf2f(unsigned short h) {
  return __uint_as_float(((unsigned)h) << 16);
}
__device__ __forceinline__ unsigned cvt_pk_bf16(float lo, float hi) {
  unsigned r;
  asm volatile("v_cvt_pk_bf16_f32 %0, %1, %2" : "=v"(r) : "v"(lo), "v"(hi));
  return r;
}
__device__ __forceinline__ unsigned short f2bf1(float x) {
  return (unsigned short)(cvt_pk_bf16(x, x) & 0xffffu);
}
__device__ __forceinline__ float fexp2(float x) {
#if __has_builtin(__builtin_amdgcn_exp2f)
  return __builtin_amdgcn_exp2f(x);
#else
  return exp2f(x);
#endif
}

typedef __attribute__((address_space(1))) const unsigned int GAS_U32;
typedef __attribute__((address_space(3))) unsigned int LAS_U32;
__device__ __forceinline__ void gl16(const void* g, void* l) {
  __builtin_amdgcn_global_load_lds((GAS_U32*)g, (LAS_U32*)l, 16, 0, 0);
}

// ---------- weight transposes via LDS 64x64 tiles (coalesced both sides) ----------
__global__ __launch_bounds__(256) void prep_kernel(const float* __restrict__ qkv_w,
                                                   const float* __restrict__ proj_w,
                                                   const float* __restrict__ fc1_w,
                                                   const float* __restrict__ fc2_w,
                                                   unsigned short* __restrict__ wq,
                                                   unsigned short* __restrict__ wp,
                                                   unsigned short* __restrict__ w1,
                                                   unsigned short* __restrict__ w2) {
  __shared__ float t[64][65];
  int b = blockIdx.x;
  const float* src;
  unsigned short* dst;
  int K, N, tb;
  if (b < 108)      { src = qkv_w;  dst = wq; K = 384; N = 1152; tb = b; }
  else if (b < 144) { src = proj_w; dst = wp; K = 384; N = 384;  tb = b - 108; }
  else if (b < 216) { src = fc1_w;  dst = w1; K = 384; N = 768;  tb = b - 144; }
  else              { src = fc2_w;  dst = w2; K = 768; N = 384;  tb = b - 216; }
  int ntn = N >> 6;
  int tk = tb / ntn, tn = tb - tk * ntn;
  int r0 = tk << 6, c0 = tn << 6;
  int rr = threadIdx.x >> 6;   // 0..3
  int cc = threadIdx.x & 63;
#pragma unroll
  for (int i = 0; i < 16; ++i)
    t[rr * 16 + i][cc] = src[(size_t)(r0 + rr * 16 + i) * N + c0 + cc];
  __syncthreads();
#pragma unroll
  for (int i = 0; i < 16; ++i)
    dst[(size_t)(c0 + rr * 16 + i) * K + r0 + cc] = f2bf1(t[cc][rr * 16 + i]);
}

// ---------- rel-pos bias expand (x8, f32) + zero-page init ----------
__global__ void rpb_expand_kernel(const float* __restrict__ rpb, float* __restrict__ biasm8,
                                  unsigned int* __restrict__ zpage) {
  if (blockIdx.x == 0 && threadIdx.x < 64) zpage[threadIdx.x] = 0u;  // 256B zero page
  int id = blockIdx.x * 256 + threadIdx.x;
  if (id >= NHEADS * 256 * 576) return;
  int head = id / 147456;
  int rem = id - head * 147456;
  int q = rem / 576;
  int kt = rem - q * 576;
  int ty = q >> 4, tx = q & 15;
  int oy = kt / 24, ox = kt - (kt / 24) * 24;
  biasm8[id] = rpb[((ty - oy + 23) * 39 + (tx - ox + 23)) * NHEADS + head] * 8.0f;
}

// ---------- LayerNorm: f32 or bf16 in -> bf16 out, one wave per row ----------
template <int BF16IN>
__global__ __launch_bounds__(256) void ln_kernel(const void* __restrict__ xv,
                                                 const float* __restrict__ g,
                                                 const float* __restrict__ b,
                                                 unsigned short* __restrict__ out) {
  int row = blockIdx.x * 4 + (threadIdx.x >> 6);
  int lane = threadIdx.x & 63;
  float v[6];
  float s = 0.f, ss = 0.f;
#pragma unroll
  for (int i = 0; i < 6; ++i) {
    int c = lane + i * 64;
    if (BF16IN) v[i] = bf2f(((const unsigned short*)xv)[(size_t)row * DIMC + c]);
    else        v[i] = ((const float*)xv)[(size_t)row * DIMC + c];
    s += v[i];
    ss += v[i] * v[i];
  }
#pragma unroll
  for (int off = 32; off; off >>= 1) {
    s += __shfl_xor(s, off);
    ss += __shfl_xor(ss, off);
  }
  float mean = s * (1.f / DIMC);
  float var = ss * (1.f / DIMC) - mean * mean;
  float rstd = rsqrtf(var + 1e-5f);
  unsigned short* outr = out + (size_t)row * DIMC;
#pragma unroll
  for (int i = 0; i < 6; ++i) {
    int c = lane + i * 64;
    outr[c] = f2bf1((v[i] - mean) * rstd * g[c] + b[c]);
  }
}

// ---------- bf16 MFMA GEMM: BK=32, 3-buffer counted-vmcnt pipeline + XCD swizzle ----------
// EPI 0: bf16 = acc+bias            (qkv)
// EPI 2: bf16 = gelu(acc+bias)      (fc1)
// EPI 3: bf16 = f32resid+acc+bias   (proj -> xa bf16)
// EPI 4: f32  = bf16resid+acc+bias  (fc2 -> final out)
template <int EPI>
__global__ __launch_bounds__(256) void gemm_bf16(const unsigned short* __restrict__ A,
                                                 const unsigned short* __restrict__ Bt,
                                                 const float* __restrict__ bias,
                                                 const void* __restrict__ residv,
                                                 void* __restrict__ outv,
                                                 int M, int N, int K) {
  __shared__ unsigned short As[3][4096];  // 3 bufs x 8KB
  __shared__ unsigned short Bs[3][4096];
  const int tid = threadIdx.x;
  // bijective XCD swizzle (nwg % 8 == 0 for all our grids)
  int id = blockIdx.y * gridDim.x + blockIdx.x;
  int chunk = (gridDim.x * gridDim.y) >> 3;
  int lid = (id & 7) * chunk + (id >> 3);
  const int m0 = (lid / gridDim.x) * 128;
  const int n0 = (lid % gridDim.x) * 128;
  const int lane = tid & 63;
  const int wave = tid >> 6;
  const int wr = wave >> 1;
  const int wc = wave & 1;
  const int l15 = lane & 15, l4 = lane >> 4;

  f32x4 acc[4][4];
#pragma unroll
  for (int i = 0; i < 4; ++i)
#pragma unroll
    for (int j = 0; j < 4; ++j) acc[i][j] = (f32x4){0.f, 0.f, 0.f, 0.f};

  const int srow = tid >> 2;
  const int scol = (tid & 3) << 3;
  const unsigned short* ga = A + (size_t)(m0 + srow) * K + scol;
  const unsigned short* gb = Bt + (size_t)(n0 + srow) * K + scol;

#define STAGE(buf, k0)                                        \
  do {                                                        \
    unsigned short* lA = As[buf] + wave * 512;                \
    unsigned short* lB = Bs[buf] + wave * 512;                \
    gl16(ga + (k0), lA);                                      \
    gl16(ga + (size_t)64 * K + (k0), lA + 2048);              \
    gl16(gb + (k0), lB);                                      \
    gl16(gb + (size_t)64 * K + (k0), lB + 2048);              \
  } while (0)

  const int nt = K >> 5;
  STAGE(0, 0);
  STAGE(1, 32);   // 8 loads/thread outstanding

  for (int t = 0; t < nt; ++t) {
    const int cur = t % 3;
    if (t + 1 < nt) {
      asm volatile("s_waitcnt vmcnt(4)" ::: "memory");  // own buf[t] loads retired (in-order)
    } else {
      asm volatile("s_waitcnt vmcnt(0)" ::: "memory");  // tail: drain remaining stage
    }
    __builtin_amdgcn_s_barrier();                       // all waves' buf[t] complete

    if (t + 2 < nt) STAGE((t + 2) % 3, (t + 2) * 32);   // overwrites buf read in iter t-1: safe

    const unsigned short* arp = As[cur] + (wr * 64 + l15) * 32 + l4 * 8;
    const unsigned short* brp = Bs[cur] + (wc * 64 + l15) * 32 + l4 * 8;
    bf16x8 af[4], bfr[4];
#pragma unroll
    for (int i = 0; i < 4; ++i) af[i] = *(const bf16x8*)(arp + i * 512);
#pragma unroll
    for (int j = 0; j < 4; ++j) bfr[j] = *(const bf16x8*)(brp + j * 512);
#pragma unroll
    for (int i = 0; i < 4; ++i)
#pragma unroll
      for (int j = 0; j < 4; ++j)
        acc[i][j] = __builtin_amdgcn_mfma_f32_16x16x32_bf16(af[i], bfr[j], acc[i][j], 0, 0, 0);
  }
#undef STAGE

#pragma unroll
  for (int j = 0; j < 4; ++j) {
    int gcol = n0 + wc * 64 + j * 16 + l15;
    float bv = bias[gcol];
#pragma unroll
    for (int i = 0; i < 4; ++i) {
#pragma unroll
      for (int r = 0; r < 4; ++r) {
        int grow = m0 + wr * 64 + i * 16 + l4 * 4 + r;
        float v = acc[i][j][r] + bv;
        size_t idx = (size_t)grow * N + gcol;
        if (EPI == 0) {
          ((unsigned short*)outv)[idx] = f2bf(v);
        } else if (EPI == 2) {
          float gv = 0.5f * v * (1.f + erff(v * 0.70710678118654752f));
          ((unsigned short*)outv)[idx] = f2bf(gv);
        } else if (EPI == 3) {
          ((unsigned short*)outv)[idx] = f2bf(((const float*)residv)[idx] + v);
        } else {  // EPI 4
          ((float*)outv)[idx] = bf2f(((const unsigned short*)residv)[idx]) + v;
        }
      }
    }
  }
}

// ---------- MFMA flash attention ----------
// Round-16 structure (K via gl16 chunk-relayout, dbuf, static-max, bias C-init, cvt_pk,
// lsum ones-MFMA) + counted-wait barrier: the tile barrier drains only LDS writes
// (lgkmcnt) and the 2 oldest vmcnt entries (K gl16s); the 8 bias loads stay in flight
// across the barrier (their latency absorbed by barrier crossing + kf ds_reads).
__global__ __launch_bounds__(256, 3) void attn_kernel(const unsigned short* __restrict__ qkv,
                                                      const float* __restrict__ biasm8,
                                                      const unsigned short* __restrict__ zpage,
                                                      unsigned short* __restrict__ att) {
  __shared__ unsigned short ks[2][4096];     // K tile relayout, dbuf (16KB)
  __shared__ unsigned short vts[2][64][72];  // V^T tile [d][kt], dbuf (18.4KB)
  __shared__ unsigned short pt[4][32][40];   // per-wave P kk-half (10.25KB)
  int bid = blockIdx.x;                       // 0..1727
  int lid = (bid & 7) * 216 + (bid >> 3);     // bijective XCD swizzle (1728 = 8*216)
  const int hw = lid >> 1;
  const int qh = lid & 1;
  const int win = hw / NHEADS;
  const int head = hw - win * NHEADS;
  const int wy = win / NWIN, wx = win - (win / NWIN) * NWIN;
  const int tid = threadIdx.x;
  const int w = tid >> 6, lane = tid & 63;
  const int l15 = lane & 15, l4 = lane >> 4;
  const float SC02 = 0.125f * 1.44269504f;
  const float C0 = -8.f * 1.44269504f;
  const bf16x8 ones = {(short)0x3F80, (short)0x3F80, (short)0x3F80, (short)0x3F80,
                       (short)0x3F80, (short)0x3F80, (short)0x3F80, (short)0x3F80};

  const int qrow0 = qh * 128 + w * 32;

  // K staging geometry: thread t covers units t and t+256
  const int skt = ((tid >> 7) << 4) + (tid & 15);  // kt for unit t (unit t+256 -> +32)
  const int sch = (tid >> 4) & 7;                  // 16B chunk (d-range sch*8..+8)

  bf16x8 qf[2][2];
#pragma unroll
  for (int jq = 0; jq < 2; ++jq) {
    int q = qrow0 + jq * 16 + l15;
    int gy = wy * WSZ + (q >> 4), gx = wx * WSZ + (q & 15);
    const unsigned short* qp = qkv + (size_t)(gy * 192 + gx) * 1152 + head * HDIM + l4 * 8;
    qf[jq][0] = *(const bf16x8*)qp;
    qf[jq][1] = *(const bf16x8*)(qp + 32);
  }

  const float* bias_base = biasm8 + (size_t)head * 147456 + (size_t)(qrow0 + l15) * 576 + l4 * 4;

  // K source pointer for tile-local kt (global token kb*64+kt); zpage if OOB
#define KSRC(ktg)                                                              \
  ({                                                                           \
    int _kt = (ktg);                                                           \
    int _oy = _kt / OWS, _ox = _kt - (_kt / OWS) * OWS;                        \
    int _gy = wy * WSZ + _oy - 4, _gx = wx * WSZ + _ox - 4;                    \
    ((unsigned)_gy < 192u && (unsigned)_gx < 192u)                             \
        ? qkv + (size_t)(_gy * 192 + _gx) * 1152 + DIMC + head * HDIM + sch * 8 \
        : zpage;                                                               \
  })
#define KSTAGE(buf, kb64)                                  \
  do {                                                     \
    unsigned short* lk = ks[buf] + w * 512;                \
    gl16(KSRC((kb64) + skt), lk);                          \
    gl16(KSRC((kb64) + skt + 32), lk + 2048);              \
  } while (0)
#define VTS_W(buf, v0v, v1v)                                           \
  do {                                                                 \
    const unsigned short* vv = (const unsigned short*)&(v0v);          \
    _Pragma("unroll") for (int j = 0; j < 8; ++j)                      \
        vts[buf][w * 16 + j][lane] = vv[j];                            \
    vv = (const unsigned short*)&(v1v);                                \
    _Pragma("unroll") for (int j = 0; j < 8; ++j)                      \
        vts[buf][w * 16 + 8 + j][lane] = vv[j];                        \
  } while (0)

  // ----- stage tile 0: K via gl16, V via regs -----
  KSTAGE(0, 0);
  {
    int kt = lane;
    int oy = kt / OWS, ox = kt - (kt / OWS) * OWS;
    int gy = wy * WSZ + oy - 4, gx = wx * WSZ + ox - 4;
    uint4 v0 = {0,0,0,0}, v1 = {0,0,0,0};
    if ((unsigned)gy < 192u && (unsigned)gx < 192u) {
      const unsigned short* gp = qkv + (size_t)(gy * 192 + gx) * 1152 + 2 * DIMC + head * HDIM + w * 16;
      v0 = *(const uint4*)gp;
      v1 = *(const uint4*)(gp + 8);
    }
    VTS_W(0, v0, v1);
  }

  f32x4 sacc[4][2];
#pragma unroll
  for (int i = 0; i < 4; ++i)
#pragma unroll
    for (int j2 = 0; j2 < 2; ++j2)
      sacc[i][j2] = *(const f32x4*)(bias_base + j2 * (16 * 576) + i * 16);

  __syncthreads();  // full drain before first tile (K gl16 + V writes + bias)

  f32x4 oacc[2][4];
#pragma unroll
  for (int i = 0; i < 2; ++i)
#pragma unroll
    for (int j = 0; j < 4; ++j) oacc[i][j] = (f32x4){0.f, 0.f, 0.f, 0.f};
  f32x4 ol[2];
  ol[0] = (f32x4){0.f, 0.f, 0.f, 0.f};
  ol[1] = (f32x4){0.f, 0.f, 0.f, 0.f};

  for (int kb = 0; kb < 9; ++kb) {
    const int cur = kb & 1;
    const bool have = kb < 8;

    // ----- async K stage for tile kb+1 into buf^1 (free since last barrier) -----
    if (have) KSTAGE(cur ^ 1, (kb + 1) * 64);

    // ----- V prefetch regs for tile kb+1 -----
    uint4 pv0 = {0,0,0,0}, pv1 = {0,0,0,0};
    if (have) {
      int kt = (kb + 1) * 64 + lane;
      int oy = kt / OWS, ox = kt - (kt / OWS) * OWS;
      int gy = wy * WSZ + oy - 4, gx = wx * WSZ + ox - 4;
      if ((unsigned)gy < 192u && (unsigned)gx < 192u) {
        const unsigned short* gp = qkv + (size_t)(gy * 192 + gx) * 1152 + 2 * DIMC + head * HDIM + w * 16;
        pv0 = *(const uint4*)gp;
        pv1 = *(const uint4*)(gp + 8);
      }
    }

    // ----- S^T = K * Q^T (C-init = bias, already in sacc) -----
#pragma unroll
    for (int kk = 0; kk < 2; ++kk) {
      const char* kbase = (const char*)ks[cur] + kk * 1024 + lane * 16;
      bf16x8 kf[4];
#pragma unroll
      for (int i = 0; i < 4; ++i)
        kf[i] = *(const bf16x8*)(kbase + i * 2048);
      __builtin_amdgcn_s_setprio(1);
#pragma unroll
      for (int i = 0; i < 4; ++i)
#pragma unroll
        for (int j2 = 0; j2 < 2; ++j2)
          sacc[i][j2] = __builtin_amdgcn_mfma_f32_16x16x32_bf16(kf[i], qf[j2][kk], sacc[i][j2], 0, 0, 0);
      __builtin_amdgcn_s_setprio(0);
    }

    // ----- P = exp2(s*SC02 + C0) (static max) -----
#pragma unroll
    for (int i = 0; i < 4; ++i)
#pragma unroll
      for (int j2 = 0; j2 < 2; ++j2)
#pragma unroll
        for (int r = 0; r < 4; ++r)
          sacc[i][j2][r] = fexp2(fmaf(sacc[i][j2][r], SC02, C0));

    // ----- PV per kk-half (+ lsum via ones-MFMA) -----
#pragma unroll
    for (int kk = 0; kk < 2; ++kk) {
#pragma unroll
      for (int i2 = 0; i2 < 2; ++i2)
#pragma unroll
        for (int j2 = 0; j2 < 2; ++j2) {
          int i = kk * 2 + i2;
          uint2 pk;
          pk.x = cvt_pk_bf16(sacc[i][j2][0], sacc[i][j2][1]);
          pk.y = cvt_pk_bf16(sacc[i][j2][2], sacc[i][j2][3]);
          *(uint2*)&pt[w][j2 * 16 + l15][i2 * 16 + l4 * 4] = pk;
        }
      bf16x8 pf[2], vf[4];
#pragma unroll
      for (int j2 = 0; j2 < 2; ++j2)
        pf[j2] = *(const bf16x8*)&pt[w][j2 * 16 + l15][l4 * 8];
#pragma unroll
      for (int jd = 0; jd < 4; ++jd)
        vf[jd] = *(const bf16x8*)&vts[cur][jd * 16 + l15][kk * 32 + l4 * 8];
      __builtin_amdgcn_s_setprio(1);
#pragma unroll
      for (int j2 = 0; j2 < 2; ++j2) {
#pragma unroll
        for (int jd = 0; jd < 4; ++jd)
          oacc[j2][jd] = __builtin_amdgcn_mfma_f32_16x16x32_bf16(pf[j2], vf[jd], oacc[j2][jd], 0, 0, 0);
        ol[j2] = __builtin_amdgcn_mfma_f32_16x16x32_bf16(pf[j2], ones, ol[j2], 0, 0, 0);
      }
      __builtin_amdgcn_s_setprio(0);
    }

    // ----- write V tile kb+1, reload bias into sacc (bias loads issued LAST) -----
    if (have) {
      VTS_W(cur ^ 1, pv0, pv1);
      const float* bp = bias_base + (kb + 1) * 64;
#pragma unroll
      for (int i = 0; i < 4; ++i)
#pragma unroll
        for (int j2 = 0; j2 < 2; ++j2)
          sacc[i][j2] = *(const f32x4*)(bp + j2 * (16 * 576) + i * 16);
    }
    // counted-wait barrier: drain LDS writes + the 2 oldest vmcnt (K gl16s);
    // leave the 8 bias loads in flight across the barrier.
    asm volatile("s_waitcnt lgkmcnt(0)" ::: "memory");
    asm volatile("s_waitcnt vmcnt(8)" ::: "memory");
    __builtin_amdgcn_s_barrier();
  }
#undef KSRC
#undef KSTAGE
#undef VTS_W

  // ----- epilogue: normalize + store (ol[j2][r] = lsum for q-row l4*4+r) -----
#pragma unroll
  for (int j2 = 0; j2 < 2; ++j2) {
#pragma unroll
    for (int r = 0; r < 4; ++r) {
      float il = 1.f / ol[j2][r];
      int q = qrow0 + j2 * 16 + l4 * 4 + r;
      int gy = wy * WSZ + (q >> 4), gx = wx * WSZ + (q & 15);
      unsigned short* op = att + (size_t)(gy * 192 + gx) * DIMC + head * HDIM + l15;
#pragma unroll
      for (int jd = 0; jd < 4; ++jd) op[jd * 16] = f2bf1(oacc[j2][jd][r] * il);
    }
  }
}

// ---------- launch ----------
extern "C" void kernel_launch(void* const* d_in, const int* in_sizes, int n_in,
                              void* d_out, int out_size, void* d_ws, size_t ws_size,
                              hipStream_t stream) {
  const float* x      = (const float*)d_in[0];
  const float* n1g    = (const float*)d_in[1];
  const float* n1b    = (const float*)d_in[2];
  const float* qkv_w  = (const float*)d_in[3];
  const float* qkv_b  = (const float*)d_in[4];
  const float* rpb    = (const float*)d_in[5];
  const float* proj_w = (const float*)d_in[6];
  const float* proj_b = (const float*)d_in[7];
  const float* n2g    = (const float*)d_in[8];
  const float* n2b    = (const float*)d_in[9];
  const float* fc1_w  = (const float*)d_in[10];
  const float* fc1_b  = (const float*)d_in[11];
  const float* fc2_w  = (const float*)d_in[12];
  const float* fc2_b  = (const float*)d_in[13];
  float* out = (float*)d_out;

  char* ws = (char*)d_ws;
  unsigned short* xn   = (unsigned short*)ws;                           // L*384 bf16; reused as biasm8+zpage during attn
  unsigned short* qkvb = (unsigned short*)(ws + 28311552);              // L*1152 bf16; first 56.6MB reused as h1
  unsigned short* xa   = (unsigned short*)(ws + 28311552 + 56623104);   // L*384 bf16 (upper qkvb, free after attn)
  unsigned short* att  = (unsigned short*)(ws + 28311552 + 84934656);   // L*384 bf16
  unsigned short* wq   = (unsigned short*)(ws + 141557760);             // 1152*384
  unsigned short* wp   = wq + 1152 * 384;                               // 384*384
  unsigned short* w1   = wp + 384 * 384;                                // 768*384
  unsigned short* w2   = w1 + 768 * 384;                                // 384*768
  float* biasm8 = (float*)ws;                          // 3.54 MB; valid between qkv GEMM and LN2
  unsigned short* zpage = (unsigned short*)(ws + 8388608);  // 256B zero page (in dead xn region)

  // tiled weight transposes (288 blocks of 64x64)
  prep_kernel<<<288, 256, 0, stream>>>(qkv_w, proj_w, fc1_w, fc2_w, wq, wp, w1, w2);

  // LN1 (f32 in)
  ln_kernel<0><<<LTOK / 4, 256, 0, stream>>>(x, n1g, n1b, xn);
  // qkv = xn @ qkv_w + b
  gemm_bf16<0><<<dim3(1152 / 128, LTOK / 128), 256, 0, stream>>>(xn, wq, qkv_b, nullptr, qkvb,
                                                                 LTOK, 1152, DIMC);
  // bias matrix expand (f32, x8) + zero-page init (both in dead xn region)
  rpb_expand_kernel<<<(NHEADS * 256 * 576 + 255) / 256, 256, 0, stream>>>(rpb, biasm8,
                                                                          (unsigned int*)zpage);
  // attention
  attn_kernel<<<dim3(NHEADS * 144 * 2), 256, 0, stream>>>(qkvb, biasm8, zpage, att);
  // xa = bf16(x + att @ proj_w + b)   [EPI 3]
  gemm_bf16<3><<<dim3(DIMC / 128, LTOK / 128), 256, 0, stream>>>(att, wp, proj_b, x, xa,
                                                                 LTOK, DIMC, DIMC);
  // LN2 (bf16 in)
  ln_kernel<1><<<LTOK / 4, 256, 0, stream>>>(xa, n2g, n2b, xn);
  // h1 = gelu(xn @ fc1_w + b)
  gemm_bf16<2><<<dim3(HIDD / 128, LTOK / 128), 256, 0, stream>>>(xn, w1, fc1_b, nullptr, qkvb,
                                                                 LTOK, HIDD, DIMC);
  // out = f32(xa + h1 @ fc2_w + b)    [EPI 4]
  gemm_bf16<4><<<dim3(DIMC / 128, LTOK / 128), 256, 0, stream>>>(qkvb, w2, fc2_b, xa, out,
                                                                 LTOK, DIMC, HIDD);
}

// Round 18
// 313.518 us; speedup vs baseline: 1.0180x; 1.0180x over previous
//
#include <hip/hip_runtime.h>

// ---------- constants (problem is fixed-shape) ----------
#define LTOK 36864     // H*W = 192*192
#define DIMC 384
#define NHEADS 6
#define HDIM 64
#define HIDD 768
#define NWIN 12        // windows per side
#define WSZ 16
#define OWS 24
#define KVTOK 576      // 24*24

using bf16x8 = __attribute__((ext_vector_type(8))) short;
using f32x4  = __attribute__((ext_vector_type(4))) float;

__device__ inline unsigned short f2bf(float f) {
  unsigned u = __float_as_uint(f);
  return (unsigned short)((u + 0x7FFFu + ((u >> 16) & 1u)) >> 16);
}
__device__ inline float bf2f(unsigned short h) {
  return __uint_as_float(((unsigned)h) << 16);
}
__device__ __forceinline__ unsigned cvt_pk_bf16(float lo, float hi) {
  unsigned r;
  asm volatile("v_cvt_pk_bf16_f32 %0, %1, %2" : "=v"(r) : "v"(lo), "v"(hi));
  return r;
}
__device__ __forceinline__ unsigned short f2bf1(float x) {
  return (unsigned short)(cvt_pk_bf16(x, x) & 0xffffu);
}
__device__ __forceinline__ float fexp2(float x) {
#if __has_builtin(__builtin_amdgcn_exp2f)
  return __builtin_amdgcn_exp2f(x);
#else
  return exp2f(x);
#endif
}

typedef __attribute__((address_space(1))) const unsigned int GAS_U32;
typedef __attribute__((address_space(3))) unsigned int LAS_U32;
__device__ __forceinline__ void gl16(const void* g, void* l) {
  __builtin_amdgcn_global_load_lds((GAS_U32*)g, (LAS_U32*)l, 16, 0, 0);
}

// ---------- weight transposes via LDS 64x64 tiles (coalesced both sides) ----------
__global__ __launch_bounds__(256) void prep_kernel(const float* __restrict__ qkv_w,
                                                   const float* __restrict__ proj_w,
                                                   const float* __restrict__ fc1_w,
                                                   const float* __restrict__ fc2_w,
                                                   unsigned short* __restrict__ wq,
                                                   unsigned short* __restrict__ wp,
                                                   unsigned short* __restrict__ w1,
                                                   unsigned short* __restrict__ w2) {
  __shared__ float t[64][65];
  int b = blockIdx.x;
  const float* src;
  unsigned short* dst;
  int K, N, tb;
  if (b < 108)      { src = qkv_w;  dst = wq; K = 384; N = 1152; tb = b; }
  else if (b < 144) { src = proj_w; dst = wp; K = 384; N = 384;  tb = b - 108; }
  else if (b < 216) { src = fc1_w;  dst = w1; K = 384; N = 768;  tb = b - 144; }
  else              { src = fc2_w;  dst = w2; K = 768; N = 384;  tb = b - 216; }
  int ntn = N >> 6;
  int tk = tb / ntn, tn = tb - tk * ntn;
  int r0 = tk << 6, c0 = tn << 6;
  int rr = threadIdx.x >> 6;   // 0..3
  int cc = threadIdx.x & 63;
#pragma unroll
  for (int i = 0; i < 16; ++i)
    t[rr * 16 + i][cc] = src[(size_t)(r0 + rr * 16 + i) * N + c0 + cc];
  __syncthreads();
#pragma unroll
  for (int i = 0; i < 16; ++i)
    dst[(size_t)(c0 + rr * 16 + i) * K + r0 + cc] = f2bf1(t[cc][rr * 16 + i]);
}

// ---------- rel-pos bias expand (x8, f32) + zero-page init ----------
__global__ void rpb_expand_kernel(const float* __restrict__ rpb, float* __restrict__ biasm8,
                                  unsigned int* __restrict__ zpage) {
  if (blockIdx.x == 0 && threadIdx.x < 64) zpage[threadIdx.x] = 0u;  // 256B zero page
  int id = blockIdx.x * 256 + threadIdx.x;
  if (id >= NHEADS * 256 * 576) return;
  int head = id / 147456;
  int rem = id - head * 147456;
  int q = rem / 576;
  int kt = rem - q * 576;
  int ty = q >> 4, tx = q & 15;
  int oy = kt / 24, ox = kt - (kt / 24) * 24;
  biasm8[id] = rpb[((ty - oy + 23) * 39 + (tx - ox + 23)) * NHEADS + head] * 8.0f;
}

// ---------- LayerNorm: f32 or bf16 in -> bf16 out, one wave per row ----------
template <int BF16IN>
__global__ __launch_bounds__(256) void ln_kernel(const void* __restrict__ xv,
                                                 const float* __restrict__ g,
                                                 const float* __restrict__ b,
                                                 unsigned short* __restrict__ out) {
  int row = blockIdx.x * 4 + (threadIdx.x >> 6);
  int lane = threadIdx.x & 63;
  float v[6];
  float s = 0.f, ss = 0.f;
#pragma unroll
  for (int i = 0; i < 6; ++i) {
    int c = lane + i * 64;
    if (BF16IN) v[i] = bf2f(((const unsigned short*)xv)[(size_t)row * DIMC + c]);
    else        v[i] = ((const float*)xv)[(size_t)row * DIMC + c];
    s += v[i];
    ss += v[i] * v[i];
  }
#pragma unroll
  for (int off = 32; off; off >>= 1) {
    s += __shfl_xor(s, off);
    ss += __shfl_xor(ss, off);
  }
  float mean = s * (1.f / DIMC);
  float var = ss * (1.f / DIMC) - mean * mean;
  float rstd = rsqrtf(var + 1e-5f);
  unsigned short* outr = out + (size_t)row * DIMC;
#pragma unroll
  for (int i = 0; i < 6; ++i) {
    int c = lane + i * 64;
    outr[c] = f2bf((v[i] - mean) * rstd * g[c] + b[c]);
  }
}

// ---------- bf16 MFMA GEMM: BK=32, 3-buffer counted-vmcnt pipeline + XCD swizzle ----------
// EPI 0: bf16 = acc+bias            (qkv)
// EPI 2: bf16 = gelu(acc+bias)      (fc1)
// EPI 3: bf16 = f32resid+acc+bias   (proj -> xa bf16)
// EPI 4: f32  = bf16resid+acc+bias  (fc2 -> final out)
template <int EPI>
__global__ __launch_bounds__(256) void gemm_bf16(const unsigned short* __restrict__ A,
                                                 const unsigned short* __restrict__ Bt,
                                                 const float* __restrict__ bias,
                                                 const void* __restrict__ residv,
                                                 void* __restrict__ outv,
                                                 int M, int N, int K) {
  __shared__ unsigned short As[3][4096];  // 3 bufs x 8KB
  __shared__ unsigned short Bs[3][4096];
  const int tid = threadIdx.x;
  // bijective XCD swizzle (nwg % 8 == 0 for all our grids)
  int id = blockIdx.y * gridDim.x + blockIdx.x;
  int chunk = (gridDim.x * gridDim.y) >> 3;
  int lid = (id & 7) * chunk + (id >> 3);
  const int m0 = (lid / gridDim.x) * 128;
  const int n0 = (lid % gridDim.x) * 128;
  const int lane = tid & 63;
  const int wave = tid >> 6;
  const int wr = wave >> 1;
  const int wc = wave & 1;
  const int l15 = lane & 15, l4 = lane >> 4;

  f32x4 acc[4][4];
#pragma unroll
  for (int i = 0; i < 4; ++i)
#pragma unroll
    for (int j = 0; j < 4; ++j) acc[i][j] = (f32x4){0.f, 0.f, 0.f, 0.f};

  const int srow = tid >> 2;
  const int scol = (tid & 3) << 3;
  const unsigned short* ga = A + (size_t)(m0 + srow) * K + scol;
  const unsigned short* gb = Bt + (size_t)(n0 + srow) * K + scol;

#define STAGE(buf, k0)                                        \
  do {                                                        \
    unsigned short* lA = As[buf] + wave * 512;                \
    unsigned short* lB = Bs[buf] + wave * 512;                \
    gl16(ga + (k0), lA);                                      \
    gl16(ga + (size_t)64 * K + (k0), lA + 2048);              \
    gl16(gb + (k0), lB);                                      \
    gl16(gb + (size_t)64 * K + (k0), lB + 2048);              \
  } while (0)

  const int nt = K >> 5;
  STAGE(0, 0);
  STAGE(1, 32);   // 8 loads/thread outstanding

  for (int t = 0; t < nt; ++t) {
    const int cur = t % 3;
    if (t + 1 < nt) {
      asm volatile("s_waitcnt vmcnt(4)" ::: "memory");  // own buf[t] loads retired (in-order)
    } else {
      asm volatile("s_waitcnt vmcnt(0)" ::: "memory");  // tail: drain remaining stage
    }
    __builtin_amdgcn_s_barrier();                       // all waves' buf[t] complete

    if (t + 2 < nt) STAGE((t + 2) % 3, (t + 2) * 32);   // overwrites buf read in iter t-1: safe

    const unsigned short* arp = As[cur] + (wr * 64 + l15) * 32 + l4 * 8;
    const unsigned short* brp = Bs[cur] + (wc * 64 + l15) * 32 + l4 * 8;
    bf16x8 af[4], bfr[4];
#pragma unroll
    for (int i = 0; i < 4; ++i) af[i] = *(const bf16x8*)(arp + i * 512);
#pragma unroll
    for (int j = 0; j < 4; ++j) bfr[j] = *(const bf16x8*)(brp + j * 512);
#pragma unroll
    for (int i = 0; i < 4; ++i)
#pragma unroll
      for (int j = 0; j < 4; ++j)
        acc[i][j] = __builtin_amdgcn_mfma_f32_16x16x32_bf16(af[i], bfr[j], acc[i][j], 0, 0, 0);
  }
#undef STAGE

#pragma unroll
  for (int j = 0; j < 4; ++j) {
    int gcol = n0 + wc * 64 + j * 16 + l15;
    float bv = bias[gcol];
#pragma unroll
    for (int i = 0; i < 4; ++i) {
#pragma unroll
      for (int r = 0; r < 4; ++r) {
        int grow = m0 + wr * 64 + i * 16 + l4 * 4 + r;
        float v = acc[i][j][r] + bv;
        size_t idx = (size_t)grow * N + gcol;
        if (EPI == 0) {
          ((unsigned short*)outv)[idx] = f2bf(v);
        } else if (EPI == 2) {
          float gv = 0.5f * v * (1.f + erff(v * 0.70710678118654752f));
          ((unsigned short*)outv)[idx] = f2bf(gv);
        } else if (EPI == 3) {
          ((unsigned short*)outv)[idx] = f2bf(((const float*)residv)[idx] + v);
        } else {  // EPI 4
          ((float*)outv)[idx] = bf2f(((const unsigned short*)residv)[idx]) + v;
        }
      }
    }
  }
}

// ---------- MFMA flash attention (round-16 best) ----------
// K via gl16 chunk-relayout (conflict-free kf reads), dbuf K/V^T, 1 barrier/tile,
// static-max softmax, bias f32 C-init, cvt_pk pack, lsum via ones-MFMA, T5 setprio.
__global__ __launch_bounds__(256, 3) void attn_kernel(const unsigned short* __restrict__ qkv,
                                                      const float* __restrict__ biasm8,
                                                      const unsigned short* __restrict__ zpage,
                                                      unsigned short* __restrict__ att) {
  __shared__ unsigned short ks[2][4096];     // K tile relayout, dbuf (16KB)
  __shared__ unsigned short vts[2][64][72];  // V^T tile [d][kt], dbuf (18.4KB)
  __shared__ unsigned short pt[4][32][40];   // per-wave P kk-half (10.25KB)
  int bid = blockIdx.x;                       // 0..1727
  int lid = (bid & 7) * 216 + (bid >> 3);     // bijective XCD swizzle (1728 = 8*216)
  const int hw = lid >> 1;
  const int qh = lid & 1;
  const int win = hw / NHEADS;
  const int head = hw - win * NHEADS;
  const int wy = win / NWIN, wx = win - (win / NWIN) * NWIN;
  const int tid = threadIdx.x;
  const int w = tid >> 6, lane = tid & 63;
  const int l15 = lane & 15, l4 = lane >> 4;
  const float SC02 = 0.125f * 1.44269504f;
  const float C0 = -8.f * 1.44269504f;
  const bf16x8 ones = {(short)0x3F80, (short)0x3F80, (short)0x3F80, (short)0x3F80,
                       (short)0x3F80, (short)0x3F80, (short)0x3F80, (short)0x3F80};

  const int qrow0 = qh * 128 + w * 32;

  // K staging geometry: thread t covers units t and t+256
  const int skt = ((tid >> 7) << 4) + (tid & 15);  // kt for unit t (unit t+256 -> +32)
  const int sch = (tid >> 4) & 7;                  // 16B chunk (d-range sch*8..+8)

  bf16x8 qf[2][2];
#pragma unroll
  for (int jq = 0; jq < 2; ++jq) {
    int q = qrow0 + jq * 16 + l15;
    int gy = wy * WSZ + (q >> 4), gx = wx * WSZ + (q & 15);
    const unsigned short* qp = qkv + (size_t)(gy * 192 + gx) * 1152 + head * HDIM + l4 * 8;
    qf[jq][0] = *(const bf16x8*)qp;
    qf[jq][1] = *(const bf16x8*)(qp + 32);
  }

  const float* bias_base = biasm8 + (size_t)head * 147456 + (size_t)(qrow0 + l15) * 576 + l4 * 4;

  // K source pointer for tile-local kt (global token kb*64+kt); zpage if OOB
#define KSRC(ktg)                                                              \
  ({                                                                           \
    int _kt = (ktg);                                                           \
    int _oy = _kt / OWS, _ox = _kt - (_kt / OWS) * OWS;                        \
    int _gy = wy * WSZ + _oy - 4, _gx = wx * WSZ + _ox - 4;                    \
    ((unsigned)_gy < 192u && (unsigned)_gx < 192u)                             \
        ? qkv + (size_t)(_gy * 192 + _gx) * 1152 + DIMC + head * HDIM + sch * 8 \
        : zpage;                                                               \
  })
#define KSTAGE(buf, kb64)                                  \
  do {                                                     \
    unsigned short* lk = ks[buf] + w * 512;                \
    gl16(KSRC((kb64) + skt), lk);                          \
    gl16(KSRC((kb64) + skt + 32), lk + 2048);              \
  } while (0)
#define VTS_W(buf, v0v, v1v)                                           \
  do {                                                                 \
    const unsigned short* vv = (const unsigned short*)&(v0v);          \
    _Pragma("unroll") for (int j = 0; j < 8; ++j)                      \
        vts[buf][w * 16 + j][lane] = vv[j];                            \
    vv = (const unsigned short*)&(v1v);                                \
    _Pragma("unroll") for (int j = 0; j < 8; ++j)                      \
        vts[buf][w * 16 + 8 + j][lane] = vv[j];                        \
  } while (0)

  // ----- stage tile 0: K via gl16, V via regs -----
  KSTAGE(0, 0);
  {
    int kt = lane;
    int oy = kt / OWS, ox = kt - (kt / OWS) * OWS;
    int gy = wy * WSZ + oy - 4, gx = wx * WSZ + ox - 4;
    uint4 v0 = {0,0,0,0}, v1 = {0,0,0,0};
    if ((unsigned)gy < 192u && (unsigned)gx < 192u) {
      const unsigned short* gp = qkv + (size_t)(gy * 192 + gx) * 1152 + 2 * DIMC + head * HDIM + w * 16;
      v0 = *(const uint4*)gp;
      v1 = *(const uint4*)(gp + 8);
    }
    VTS_W(0, v0, v1);
  }

  f32x4 sacc[4][2];
#pragma unroll
  for (int i = 0; i < 4; ++i)
#pragma unroll
    for (int j2 = 0; j2 < 2; ++j2)
      sacc[i][j2] = *(const f32x4*)(bias_base + j2 * (16 * 576) + i * 16);

  __syncthreads();  // drains gl16 (vmcnt) + LDS writes

  f32x4 oacc[2][4];
#pragma unroll
  for (int i = 0; i < 2; ++i)
#pragma unroll
    for (int j = 0; j < 4; ++j) oacc[i][j] = (f32x4){0.f, 0.f, 0.f, 0.f};
  f32x4 ol[2];
  ol[0] = (f32x4){0.f, 0.f, 0.f, 0.f};
  ol[1] = (f32x4){0.f, 0.f, 0.f, 0.f};

  for (int kb = 0; kb < 9; ++kb) {
    const int cur = kb & 1;
    const bool have = kb < 8;

    // ----- async K stage for tile kb+1 into buf^1 (free since last barrier) -----
    if (have) KSTAGE(cur ^ 1, (kb + 1) * 64);

    // ----- V prefetch regs for tile kb+1 -----
    uint4 pv0 = {0,0,0,0}, pv1 = {0,0,0,0};
    if (have) {
      int kt = (kb + 1) * 64 + lane;
      int oy = kt / OWS, ox = kt - (kt / OWS) * OWS;
      int gy = wy * WSZ + oy - 4, gx = wx * WSZ + ox - 4;
      if ((unsigned)gy < 192u && (unsigned)gx < 192u) {
        const unsigned short* gp = qkv + (size_t)(gy * 192 + gx) * 1152 + 2 * DIMC + head * HDIM + w * 16;
        pv0 = *(const uint4*)gp;
        pv1 = *(const uint4*)(gp + 8);
      }
    }

    // ----- S^T = K * Q^T (C-init = bias, already in sacc) -----
#pragma unroll
    for (int kk = 0; kk < 2; ++kk) {
      const char* kbase = (const char*)ks[cur] + kk * 1024 + lane * 16;
      bf16x8 kf[4];
#pragma unroll
      for (int i = 0; i < 4; ++i)
        kf[i] = *(const bf16x8*)(kbase + i * 2048);
      __builtin_amdgcn_s_setprio(1);
#pragma unroll
      for (int i = 0; i < 4; ++i)
#pragma unroll
        for (int j2 = 0; j2 < 2; ++j2)
          sacc[i][j2] = __builtin_amdgcn_mfma_f32_16x16x32_bf16(kf[i], qf[j2][kk], sacc[i][j2], 0, 0, 0);
      __builtin_amdgcn_s_setprio(0);
    }

    // ----- P = exp2(s*SC02 + C0) (static max) -----
#pragma unroll
    for (int i = 0; i < 4; ++i)
#pragma unroll
      for (int j2 = 0; j2 < 2; ++j2)
#pragma unroll
        for (int r = 0; r < 4; ++r)
          sacc[i][j2][r] = fexp2(fmaf(sacc[i][j2][r], SC02, C0));

    // ----- PV per kk-half (+ lsum via ones-MFMA) -----
#pragma unroll
    for (int kk = 0; kk < 2; ++kk) {
#pragma unroll
      for (int i2 = 0; i2 < 2; ++i2)
#pragma unroll
        for (int j2 = 0; j2 < 2; ++j2) {
          int i = kk * 2 + i2;
          uint2 pk;
          pk.x = cvt_pk_bf16(sacc[i][j2][0], sacc[i][j2][1]);
          pk.y = cvt_pk_bf16(sacc[i][j2][2], sacc[i][j2][3]);
          *(uint2*)&pt[w][j2 * 16 + l15][i2 * 16 + l4 * 4] = pk;
        }
      bf16x8 pf[2], vf[4];
#pragma unroll
      for (int j2 = 0; j2 < 2; ++j2)
        pf[j2] = *(const bf16x8*)&pt[w][j2 * 16 + l15][l4 * 8];
#pragma unroll
      for (int jd = 0; jd < 4; ++jd)
        vf[jd] = *(const bf16x8*)&vts[cur][jd * 16 + l15][kk * 32 + l4 * 8];
      __builtin_amdgcn_s_setprio(1);
#pragma unroll
      for (int j2 = 0; j2 < 2; ++j2) {
#pragma unroll
        for (int jd = 0; jd < 4; ++jd)
          oacc[j2][jd] = __builtin_amdgcn_mfma_f32_16x16x32_bf16(pf[j2], vf[jd], oacc[j2][jd], 0, 0, 0);
        ol[j2] = __builtin_amdgcn_mfma_f32_16x16x32_bf16(pf[j2], ones, ol[j2], 0, 0, 0);
      }
      __builtin_amdgcn_s_setprio(0);
    }

    // ----- write V tile kb+1, reload bias into sacc -----
    if (have) {
      VTS_W(cur ^ 1, pv0, pv1);
      const float* bp = bias_base + (kb + 1) * 64;
#pragma unroll
      for (int i = 0; i < 4; ++i)
#pragma unroll
        for (int j2 = 0; j2 < 2; ++j2)
          sacc[i][j2] = *(const f32x4*)(bp + j2 * (16 * 576) + i * 16);
    }
    __syncthreads();  // single barrier per tile (drains gl16 K + V writes)
  }
#undef KSRC
#undef KSTAGE
#undef VTS_W

  // ----- epilogue: normalize + store (ol[j2][r] = lsum for q-row l4*4+r) -----
#pragma unroll
  for (int j2 = 0; j2 < 2; ++j2) {
#pragma unroll
    for (int r = 0; r < 4; ++r) {
      float il = 1.f / ol[j2][r];
      int q = qrow0 + j2 * 16 + l4 * 4 + r;
      int gy = wy * WSZ + (q >> 4), gx = wx * WSZ + (q & 15);
      unsigned short* op = att + (size_t)(gy * 192 + gx) * DIMC + head * HDIM + l15;
#pragma unroll
      for (int jd = 0; jd < 4; ++jd) op[jd * 16] = f2bf1(oacc[j2][jd][r] * il);
    }
  }
}

// ---------- launch ----------
extern "C" void kernel_launch(void* const* d_in, const int* in_sizes, int n_in,
                              void* d_out, int out_size, void* d_ws, size_t ws_size,
                              hipStream_t stream) {
  const float* x      = (const float*)d_in[0];
  const float* n1g    = (const float*)d_in[1];
  const float* n1b    = (const float*)d_in[2];
  const float* qkv_w  = (const float*)d_in[3];
  const float* qkv_b  = (const float*)d_in[4];
  const float* rpb    = (const float*)d_in[5];
  const float* proj_w = (const float*)d_in[6];
  const float* proj_b = (const float*)d_in[7];
  const float* n2g    = (const float*)d_in[8];
  const float* n2b    = (const float*)d_in[9];
  const float* fc1_w  = (const float*)d_in[10];
  const float* fc1_b  = (const float*)d_in[11];
  const float* fc2_w  = (const float*)d_in[12];
  const float* fc2_b  = (const float*)d_in[13];
  float* out = (float*)d_out;

  char* ws = (char*)d_ws;
  unsigned short* xn   = (unsigned short*)ws;                           // L*384 bf16; reused as biasm8+zpage during attn
  unsigned short* qkvb = (unsigned short*)(ws + 28311552);              // L*1152 bf16; first 56.6MB reused as h1
  unsigned short* xa   = (unsigned short*)(ws + 28311552 + 56623104);   // L*384 bf16 (upper qkvb, free after attn)
  unsigned short* att  = (unsigned short*)(ws + 28311552 + 84934656);   // L*384 bf16
  unsigned short* wq   = (unsigned short*)(ws + 141557760);             // 1152*384
  unsigned short* wp   = wq + 1152 * 384;                               // 384*384
  unsigned short* w1   = wp + 384 * 384;                                // 768*384
  unsigned short* w2   = w1 + 768 * 384;                                // 384*768
  float* biasm8 = (float*)ws;                          // 3.54 MB; valid between qkv GEMM and LN2
  unsigned short* zpage = (unsigned short*)(ws + 8388608);  // 256B zero page (in dead xn region)

  // tiled weight transposes (288 blocks of 64x64)
  prep_kernel<<<288, 256, 0, stream>>>(qkv_w, proj_w, fc1_w, fc2_w, wq, wp, w1, w2);

  // LN1 (f32 in)
  ln_kernel<0><<<LTOK / 4, 256, 0, stream>>>(x, n1g, n1b, xn);
  // qkv = xn @ qkv_w + b
  gemm_bf16<0><<<dim3(1152 / 128, LTOK / 128), 256, 0, stream>>>(xn, wq, qkv_b, nullptr, qkvb,
                                                                 LTOK, 1152, DIMC);
  // bias matrix expand (f32, x8) + zero-page init (both in dead xn region)
  rpb_expand_kernel<<<(NHEADS * 256 * 576 + 255) / 256, 256, 0, stream>>>(rpb, biasm8,
                                                                          (unsigned int*)zpage);
  // attention
  attn_kernel<<<dim3(NHEADS * 144 * 2), 256, 0, stream>>>(qkvb, biasm8, zpage, att);
  // xa = bf16(x + att @ proj_w + b)   [EPI 3]
  gemm_bf16<3><<<dim3(DIMC / 128, LTOK / 128), 256, 0, stream>>>(att, wp, proj_b, x, xa,
                                                                 LTOK, DIMC, DIMC);
  // LN2 (bf16 in)
  ln_kernel<1><<<LTOK / 4, 256, 0, stream>>>(xa, n2g, n2b, xn);
  // h1 = gelu(xn @ fc1_w + b)
  gemm_bf16<2><<<dim3(HIDD / 128, LTOK / 128), 256, 0, stream>>>(xn, w1, fc1_b, nullptr, qkvb,
                                                                 LTOK, HIDD, DIMC);
  // out = f32(xa + h1 @ fc2_w + b)    [EPI 4]
  gemm_bf16<4><<<dim3(DIMC / 128, LTOK / 128), 256, 0, stream>>>(qkvb, w2, fc2_b, xa, out,
                                                                 LTOK, DIMC, HIDD);
}